// Round 1
// baseline (1687.637 us; speedup 1.0000x reference)
//
#include <hip/hip_runtime.h>
#include <hip/hip_bf16.h>
#include <math.h>

// ---------------- problem constants ----------------
#define B_       8
#define T_       2048
#define N_TOK    (B_*T_)        // 16384 tokens
#define D_       1024
#define E_       8
#define H_       4096
#define TOPK     2
#define R_       (N_TOK*TOPK)   // 32768 gathered rows
#define OUT_ELEMS ((size_t)N_TOK*D_)

// ---------------- GEMM tiling ----------------
#define BM 128
#define BN 128
#define BK 32                    // LDS panel depth (row stride stays 64B: conflict-free)
#define KSTEP 64                 // K advance per barrier pair (2 panels)
#define PANEL (BM*BK)            // 4096 shorts = 8KB per panel
#define MAXT 264                 // sum_e ceil(n_e/128) <= 263; 264 safe
#define NPH 3                    // phases (Hbuf reuse to fit ws)
#define TPP 88                   // tiles per phase, 3*88 = 264
#define HROWS (TPP*BM)           // 11264 rows per phase

typedef __attribute__((ext_vector_type(8))) short short8;
typedef __attribute__((ext_vector_type(4))) float floatx4;
typedef const __attribute__((address_space(1))) void* gptr_t;
typedef __attribute__((address_space(3))) void* lptr_t;

__device__ __forceinline__ void gl16(const void* g, void* l) {
  // async global->LDS, 16B/lane; LDS dest = wave-uniform base + lane*16
  __builtin_amdgcn_global_load_lds((gptr_t)g, (lptr_t)l, 16, 0, 0);
}

__device__ __forceinline__ unsigned short f2bf(float f) {
  union { float f; unsigned int u; } v; v.f = f;
  unsigned int u = v.u;
  u += 0x7FFFu + ((u >> 16) & 1u);   // RNE
  return (unsigned short)(u >> 16);
}

// tanh-GELU via its sigmoid identity:
//   0.5v(1+tanh(u)) == v * sigmoid(2u),  2u = 1.5957691216(v + 0.044715 v^3)
// exp(-2u) computed as exp2( v * (-log2e*1.5957691216*(1 + 0.044715 v^2)) )
// ~7 VALU ops vs ~35 for libm tanhf.  (constants: 1.5957691216*log2e = 2.30220830,
//  0.044715*1.5957691216*log2e = 0.10294325)
__device__ __forceinline__ float gelu_tanh(float v) {
  float u = __builtin_fmaf(v * v, -0.10294325f, -2.30220830f);
  float p = __builtin_amdgcn_exp2f(v * u);
  return v * __builtin_amdgcn_rcpf(1.0f + p);
}

// ---------------- router: one wave per token (NO global atomics) ----------------
__global__ __launch_bounds__(256) void router_kernel(
    const float* __restrict__ x, const int* __restrict__ city_idx_p,
    const float* __restrict__ dt, const float* __restrict__ dd,
    const float* __restrict__ drg, const float* __restrict__ de,
    const float* __restrict__ cemb, const float* __restrict__ Wr,
    const float* __restrict__ br,
    float* __restrict__ gate1, int* __restrict__ topk_e,
    float* __restrict__ topk_w)
{
  const int wid = threadIdx.x >> 6, lane = threadIdx.x & 63;
  const int token = blockIdx.x * 4 + wid;

  float acc[E_];
#pragma unroll
  for (int e = 0; e < E_; e++) acc[e] = 0.f;

  const float* ce = cemb + (*city_idx_p) * 32;

  // ng = number of float4 groups; lane handles groups lane, lane+64, ...
  auto fma_seg4 = [&](const float* src, int ng, int base) {
    for (int i = lane; i < ng; i += 64) {
      float4 f = ((const float4*)src)[i];
      const float4* wv = (const float4*)(Wr + (size_t)(base + i * 4) * E_);
      float4 w0 = wv[0], w1 = wv[1], w2 = wv[2], w3 = wv[3];
      float4 w4 = wv[4], w5 = wv[5], w6 = wv[6], w7 = wv[7];
      acc[0] += f.x * w0.x; acc[1] += f.x * w0.y; acc[2] += f.x * w0.z; acc[3] += f.x * w0.w;
      acc[4] += f.x * w1.x; acc[5] += f.x * w1.y; acc[6] += f.x * w1.z; acc[7] += f.x * w1.w;
      acc[0] += f.y * w2.x; acc[1] += f.y * w2.y; acc[2] += f.y * w2.z; acc[3] += f.y * w2.w;
      acc[4] += f.y * w3.x; acc[5] += f.y * w3.y; acc[6] += f.y * w3.z; acc[7] += f.y * w3.w;
      acc[0] += f.z * w4.x; acc[1] += f.z * w4.y; acc[2] += f.z * w4.z; acc[3] += f.z * w4.w;
      acc[4] += f.z * w5.x; acc[5] += f.z * w5.y; acc[6] += f.z * w5.z; acc[7] += f.z * w5.w;
      acc[0] += f.w * w6.x; acc[1] += f.w * w6.y; acc[2] += f.w * w6.z; acc[3] += f.w * w6.w;
      acc[4] += f.w * w7.x; acc[5] += f.w * w7.y; acc[6] += f.w * w7.z; acc[7] += f.w * w7.w;
    }
  };
  fma_seg4(x  + (size_t)token * D_,  D_ / 4, 0);
  fma_seg4(ce,                       32 / 4, 1024);
  fma_seg4(dt + (size_t)token * 256, 256 / 4, 1056);
  fma_seg4(dd + (size_t)token * 256, 256 / 4, 1312);
  fma_seg4(drg+ (size_t)token * 128, 128 / 4, 1568);
  fma_seg4(de + (size_t)token * 128, 128 / 4, 1696);

#pragma unroll
  for (int e = 0; e < E_; e++) {
    float v = acc[e];
#pragma unroll
    for (int s = 32; s > 0; s >>= 1) v += __shfl_xor(v, s, 64);
    acc[e] = v + br[e];
  }

  if (lane == 0) {
    float mx = acc[0];
#pragma unroll
    for (int e = 1; e < E_; e++) mx = fmaxf(mx, acc[e]);
    float s = 0.f, ex[E_];
#pragma unroll
    for (int e = 0; e < E_; e++) { ex[e] = expf(acc[e] - mx); s += ex[e]; }
    float inv = 1.f / s;
#pragma unroll
    for (int e = 0; e < E_; e++) gate1[(size_t)token * E_ + e] = ex[e] * inv;

    int e0 = 0;
#pragma unroll
    for (int e = 1; e < E_; e++) if (acc[e] > acc[e0]) e0 = e;
    int e1 = (e0 == 0) ? 1 : 0;
#pragma unroll
    for (int e = 0; e < E_; e++) if (e != e0 && acc[e] > acc[e1]) e1 = e;
    float t2 = expf(acc[e1] - acc[e0]);
    float w0 = 1.f / (1.f + t2), w1 = t2 / (1.f + t2);
    topk_e[token * 2]     = e0; topk_e[token * 2 + 1] = e1;
    topk_w[token * 2]     = w0; topk_w[token * 2 + 1] = w1;
  }
}

// ---------------- histogram: LDS bins, 8 global atomics per block ----------------
__global__ __launch_bounds__(256) void hist_kernel(const int* __restrict__ topk_e,
                                                   int* __restrict__ counts)
{
  __shared__ int h[E_];
  const int t = threadIdx.x;
  if (t < E_) h[t] = 0;
  __syncthreads();
  const int base = blockIdx.x * 1024 + t;
#pragma unroll
  for (int j = 0; j < 4; j++) atomicAdd(&h[topk_e[base + j * 256]], 1);
  __syncthreads();
  if (t < E_ && h[t] > 0) atomicAdd(&counts[t], h[t]);
}

// ---------------- build padded tile table ----------------
__global__ void build_tiles_kernel(const int* __restrict__ counts, int* pbase,
                                   int* cursors, int* tile_expert, int* num_tiles)
{
  if (threadIdx.x == 0 && blockIdx.x == 0) {
    int t = 0;
    for (int e = 0; e < E_; e++) {
      pbase[e] = t * BM;
      cursors[e] = 0;
      int nt = (counts[e] + BM - 1) / BM;
      for (int i = 0; i < nt; i++) tile_expert[t++] = e;
    }
    *num_tiles = t;
  }
}

// ---------------- scatter token->padded row (hierarchical reservation) ----------------
__global__ __launch_bounds__(256) void scatter_kernel(
    const int* __restrict__ topk_e, const float* __restrict__ topk_w,
    const int* __restrict__ pbase, int* __restrict__ cursors,
    int* __restrict__ prow_token, float* __restrict__ prow_w)
{
  __shared__ int wcnt[4][E_];
  __shared__ int wbase[4][E_];
  const int t = threadIdx.x, lane = t & 63, wid = t >> 6;
  if (t < 32) ((int*)wcnt)[t] = 0;
  __syncthreads();

  const int idx = blockIdx.x * 256 + t;
  const int e = topk_e[idx];
  const float w = topk_w[idx];

  // same-e lane mask via 3 ballots (e has 3 bits)
  unsigned long long b0 = __ballot(e & 1);
  unsigned long long b1 = __ballot(e & 2);
  unsigned long long b2 = __ballot(e & 4);
  unsigned long long m = ((e & 1) ? b0 : ~b0) & ((e & 2) ? b1 : ~b1) & ((e & 4) ? b2 : ~b2);
  unsigned long long below = ((unsigned long long)1 << lane) - 1;
  const int rank = __popcll(m & below);
  if (rank == 0) wcnt[wid][e] = __popcll(m);
  __syncthreads();

  if (t < E_) {
    int run = 0, tmp[4];
#pragma unroll
    for (int w2 = 0; w2 < 4; w2++) { tmp[w2] = run; run += wcnt[w2][t]; }
    int gb = (run > 0) ? atomicAdd(&cursors[t], run) : 0;
#pragma unroll
    for (int w2 = 0; w2 < 4; w2++) wbase[w2][t] = gb + tmp[w2];
  }
  __syncthreads();

  const int pos = pbase[e] + wbase[wid][e] + rank;
  prow_token[pos] = idx >> 1;
  prow_w[pos] = w;
}

// ---------------- x f32 -> bf16 ----------------
__global__ __launch_bounds__(256) void xconv_kernel(const float* __restrict__ x,
                                                    unsigned short* __restrict__ xbf)
{
  size_t i = ((size_t)blockIdx.x * 256 + threadIdx.x) * 8;
  float4 a = ((const float4*)(x + i))[0], b = ((const float4*)(x + i))[1];
  unsigned short o[8] = {f2bf(a.x), f2bf(a.y), f2bf(a.z), f2bf(a.w),
                         f2bf(b.x), f2bf(b.y), f2bf(b.z), f2bf(b.w)};
  *(short8*)(xbf + i) = *(short8*)o;
}

// ---------------- W [e][K][N] f32  ->  Wt [e][N][K] bf16 ----------------
__global__ __launch_bounds__(256) void wtrans_kernel(
    const float* __restrict__ W, unsigned short* __restrict__ Wt, int K, int N)
{
  const int e = blockIdx.z, k0 = blockIdx.x * 32, n0 = blockIdx.y * 128;
  __shared__ unsigned short Ls[128 * 40];   // [n][k], stride 40
  const int t = threadIdx.x;
  const int kr = t >> 3;
  const int cg = (t & 7) * 16;
  const float* src = W + ((size_t)e * K + k0 + kr) * N + n0 + cg;
  float4 f0 = ((const float4*)src)[0];
  float4 f1 = ((const float4*)src)[1];
  float4 f2 = ((const float4*)src)[2];
  float4 f3 = ((const float4*)src)[3];
  float v[16] = {f0.x,f0.y,f0.z,f0.w, f1.x,f1.y,f1.z,f1.w,
                 f2.x,f2.y,f2.z,f2.w, f3.x,f3.y,f3.z,f3.w};
#pragma unroll
  for (int j = 0; j < 16; j++) Ls[(cg + j) * 40 + kr] = f2bf(v[j]);
  __syncthreads();
  const int r = t >> 1, hh = (t & 1) * 16;
  unsigned short* dst = Wt + ((size_t)e * N + n0 + r) * K + k0 + hh;
  short8 o0 = *(short8*)&Ls[r * 40 + hh];
  short8 o1 = *(short8*)&Ls[r * 40 + hh + 8];
  *(short8*)dst       = o0;
  *(short8*)(dst + 8) = o1;
}

// ---------------- GEMM1: H = gelu(Xg @ Wfc[e] + bfc[e]) ----------------
__global__ __launch_bounds__(256) void fc_gemm_kernel(
    const unsigned short* __restrict__ xbf, const unsigned short* __restrict__ Wt,
    const float* __restrict__ bfc, const int* __restrict__ prow_token,
    const int* __restrict__ tile_expert, const int* __restrict__ num_tiles_p,
    const unsigned short* __restrict__ zrow,
    unsigned short* __restrict__ H, int tile_base)
{
  const int tile = tile_base + blockIdx.y;
  if (tile >= *num_tiles_p) return;
  const int e  = tile_expert[tile];
  const int n0 = blockIdx.x * BN;
  const int ltile = tile - tile_base;

  __shared__ unsigned short As[2 * PANEL];   // two [row][k] stride-32 panels
  __shared__ unsigned short Bs[2 * PANEL];
  __shared__ int toks[BM];

  const int t = threadIdx.x;
  if (t < BM) toks[t] = prow_token[tile * BM + t];
  __syncthreads();

  const int lane = t & 63, wid = t >> 6;
  const int ko = (lane & 3) * 8;
  const int r0 = wid * 32 + (lane >> 2);
  const int tk0 = toks[r0], tk1 = toks[r0 + 16];
  const unsigned short* pa0 = (tk0 >= 0) ? xbf + (size_t)tk0 * D_ + ko : zrow + ko;
  const unsigned short* pa1 = (tk1 >= 0) ? xbf + (size_t)tk1 * D_ + ko : zrow + ko;
  const unsigned short* WtE = Wt + (size_t)e * H_ * D_;
  const unsigned short* pb0 = WtE + (size_t)(n0 + r0) * D_ + ko;
  const unsigned short* pb1 = pb0 + (size_t)16 * D_;
  unsigned short* lA0 = &As[wid * 1024];
  unsigned short* lA1 = &As[wid * 1024 + 512];
  unsigned short* lB0 = &Bs[wid * 1024];
  unsigned short* lB1 = &Bs[wid * 1024 + 512];

  const int wm = (wid >> 1) * 64, wn = (wid & 1) * 64;
  const int lrow = lane & 15, quad = lane >> 4;

  floatx4 acc[4][4];
#pragma unroll
  for (int i = 0; i < 4; i++)
#pragma unroll
    for (int j = 0; j < 4; j++) acc[i][j] = (floatx4){0.f, 0.f, 0.f, 0.f};

  for (int k0 = 0; k0 < D_; k0 += KSTEP) {
    // stage two BK=32 panels, ONE barrier pair per 64 K
    gl16(pa0 + k0,      lA0);
    gl16(pa1 + k0,      lA1);
    gl16(pb0 + k0,      lB0);
    gl16(pb1 + k0,      lB1);
    gl16(pa0 + k0 + 32, lA0 + PANEL);
    gl16(pa1 + k0 + 32, lA1 + PANEL);
    gl16(pb0 + k0 + 32, lB0 + PANEL);
    gl16(pb1 + k0 + 32, lB1 + PANEL);
    __syncthreads();

#pragma unroll
    for (int kk = 0; kk < 2; kk++) {
      short8 af[4], bfr[4];
#pragma unroll
      for (int mi = 0; mi < 4; mi++)
        af[mi]  = *(const short8*)&As[kk * PANEL + (wm + mi * 16 + lrow) * BK + quad * 8];
#pragma unroll
      for (int ni = 0; ni < 4; ni++)
        bfr[ni] = *(const short8*)&Bs[kk * PANEL + (wn + ni * 16 + lrow) * BK + quad * 8];
#pragma unroll
      for (int mi = 0; mi < 4; mi++)
#pragma unroll
        for (int ni = 0; ni < 4; ni++)
          acc[mi][ni] = __builtin_amdgcn_mfma_f32_16x16x32_bf16(af[mi], bfr[ni], acc[mi][ni], 0, 0, 0);
    }
    __syncthreads();
  }

  const float* bias = bfc + (size_t)e * H_ + n0;
#pragma unroll
  for (int mi = 0; mi < 4; mi++) {
    int row = wm + mi * 16 + quad * 4;
#pragma unroll
    for (int ni = 0; ni < 4; ni++) {
      int col = wn + ni * 16 + lrow;
      float b = bias[col];
#pragma unroll
      for (int r = 0; r < 4; r++) {
        float v = acc[mi][ni][r] + b;
        H[(size_t)(ltile * BM + row + r) * H_ + n0 + col] = f2bf(gelu_tanh(v));
      }
    }
  }
}

// ---------------- GEMM2: out += w * (H @ Wproj[e] + bproj[e]) ----------------
__global__ __launch_bounds__(256) void proj_gemm_kernel(
    const unsigned short* __restrict__ H, const unsigned short* __restrict__ Wt,
    const float* __restrict__ bpj, const int* __restrict__ prow_token,
    const float* __restrict__ prow_w, const int* __restrict__ tile_expert,
    const int* __restrict__ num_tiles_p, float* __restrict__ out, int tile_base)
{
  const int tile = tile_base + blockIdx.y;
  if (tile >= *num_tiles_p) return;
  const int e  = tile_expert[tile];
  const int n0 = blockIdx.x * BN;
  const int ltile = tile - tile_base;

  __shared__ unsigned short As[2 * PANEL];
  __shared__ unsigned short Bs[2 * PANEL];
  __shared__ int   toks[BM];
  __shared__ float wgt[BM];

  const int t = threadIdx.x;
  if (t < BM) { toks[t] = prow_token[tile * BM + t]; wgt[t] = prow_w[tile * BM + t]; }
  __syncthreads();

  const int lane = t & 63, wid = t >> 6;
  const int ko = (lane & 3) * 8;
  const int r0 = wid * 32 + (lane >> 2);
  const unsigned short* pa0 = H + (size_t)(ltile * BM + r0) * H_ + ko;
  const unsigned short* pa1 = pa0 + (size_t)16 * H_;
  const unsigned short* WtE = Wt + (size_t)e * D_ * H_;
  const unsigned short* pb0 = WtE + (size_t)(n0 + r0) * H_ + ko;
  const unsigned short* pb1 = pb0 + (size_t)16 * H_;
  unsigned short* lA0 = &As[wid * 1024];
  unsigned short* lA1 = &As[wid * 1024 + 512];
  unsigned short* lB0 = &Bs[wid * 1024];
  unsigned short* lB1 = &Bs[wid * 1024 + 512];

  const int wm = (wid >> 1) * 64, wn = (wid & 1) * 64;
  const int lrow = lane & 15, quad = lane >> 4;

  floatx4 acc[4][4];
#pragma unroll
  for (int i = 0; i < 4; i++)
#pragma unroll
    for (int j = 0; j < 4; j++) acc[i][j] = (floatx4){0.f, 0.f, 0.f, 0.f};

  for (int k0 = 0; k0 < H_; k0 += KSTEP) {
    gl16(pa0 + k0,      lA0);
    gl16(pa1 + k0,      lA1);
    gl16(pb0 + k0,      lB0);
    gl16(pb1 + k0,      lB1);
    gl16(pa0 + k0 + 32, lA0 + PANEL);
    gl16(pa1 + k0 + 32, lA1 + PANEL);
    gl16(pb0 + k0 + 32, lB0 + PANEL);
    gl16(pb1 + k0 + 32, lB1 + PANEL);
    __syncthreads();

#pragma unroll
    for (int kk = 0; kk < 2; kk++) {
      short8 af[4], bfr[4];
#pragma unroll
      for (int mi = 0; mi < 4; mi++)
        af[mi]  = *(const short8*)&As[kk * PANEL + (wm + mi * 16 + lrow) * BK + quad * 8];
#pragma unroll
      for (int ni = 0; ni < 4; ni++)
        bfr[ni] = *(const short8*)&Bs[kk * PANEL + (wn + ni * 16 + lrow) * BK + quad * 8];
#pragma unroll
      for (int mi = 0; mi < 4; mi++)
#pragma unroll
        for (int ni = 0; ni < 4; ni++)
          acc[mi][ni] = __builtin_amdgcn_mfma_f32_16x16x32_bf16(af[mi], bfr[ni], acc[mi][ni], 0, 0, 0);
    }
    __syncthreads();
  }

  const float* bias = bpj + (size_t)e * D_ + n0;
#pragma unroll
  for (int mi = 0; mi < 4; mi++) {
    int row = wm + mi * 16 + quad * 4;
#pragma unroll
    for (int ni = 0; ni < 4; ni++) {
      int col = wn + ni * 16 + lrow;
      float b = bias[col];
#pragma unroll
      for (int r = 0; r < 4; r++) {
        int rr = row + r;
        int tok = toks[rr];
        if (tok >= 0) {
          float v = (acc[mi][ni][r] + b) * wgt[rr];
          atomicAdd(&out[(size_t)tok * D_ + n0 + col], v);
        }
      }
    }
  }
}

// ---------------- host launcher ----------------
extern "C" void kernel_launch(void* const* d_in, const int* in_sizes, int n_in,
                              void* d_out, int out_size, void* d_ws, size_t ws_size,
                              hipStream_t stream)
{
  const float* x    = (const float*)d_in[0];
  const int*   cidx = (const int*)d_in[1];
  const float* dt   = (const float*)d_in[2];
  const float* dd   = (const float*)d_in[3];
  const float* drg  = (const float*)d_in[4];
  const float* de   = (const float*)d_in[5];
  const float* cemb = (const float*)d_in[6];
  const float* Wr   = (const float*)d_in[7];
  const float* br   = (const float*)d_in[8];
  const float* Wfc  = (const float*)d_in[9];
  const float* bfc  = (const float*)d_in[10];
  const float* Wpj  = (const float*)d_in[11];
  const float* bpj  = (const float*)d_in[12];

  float* out   = (float*)d_out;
  float* gate1 = out + OUT_ELEMS;

  char* ws = (char*)d_ws;
  size_t off = 0;
  auto take = [&](size_t bytes) { size_t r = off; off += (bytes + 255) & ~(size_t)255; return r; };
  unsigned short* Hbuf  = (unsigned short*)(ws + take((size_t)HROWS * H_ * 2));   // 92.3 MB
  unsigned short* xbf   = (unsigned short*)(ws + take((size_t)N_TOK * D_ * 2));   // 33.6 MB
  unsigned short* WtFc  = (unsigned short*)(ws + take((size_t)E_ * H_ * D_ * 2)); // 67.1 MB
  unsigned short* WtPj  = (unsigned short*)(ws + take((size_t)E_ * D_ * H_ * 2)); // 67.1 MB
  int*   topk_e      = (int*)  (ws + take((size_t)R_ * 4));
  float* topk_w      = (float*)(ws + take((size_t)R_ * 4));
  int*   prow_token  = (int*)  (ws + take((size_t)(MAXT * BM) * 4));
  float* prow_w      = (float*)(ws + take((size_t)(MAXT * BM) * 4));
  unsigned short* zrow = (unsigned short*)(ws + take(4096));
  int*   counts      = (int*)  (ws + take(E_ * 4));
  int*   cursors     = (int*)  (ws + take(E_ * 4));
  int*   pbase       = (int*)  (ws + take(E_ * 4));
  int*   tile_expert = (int*)  (ws + take(MAXT * 4));
  int*   num_tiles   = (int*)  (ws + take(4));
  (void)ws_size; (void)in_sizes; (void)n_in; (void)out_size;

  hipMemsetAsync(d_out, 0, OUT_ELEMS * 4, stream);
  hipMemsetAsync(counts, 0, E_ * 4, stream);
  hipMemsetAsync(prow_token, 0xFF, (size_t)(MAXT * BM) * 4, stream);
  hipMemsetAsync(zrow, 0, 4096, stream);

  xconv_kernel<<<(N_TOK * D_) / (256 * 8), 256, 0, stream>>>(x, xbf);
  wtrans_kernel<<<dim3(D_ / 32, H_ / 128, E_), 256, 0, stream>>>(Wfc, WtFc, D_, H_);
  wtrans_kernel<<<dim3(H_ / 32, D_ / 128, E_), 256, 0, stream>>>(Wpj, WtPj, H_, D_);

  router_kernel<<<N_TOK / 4, 256, 0, stream>>>(x, cidx, dt, dd, drg, de, cemb, Wr, br,
                                               gate1, topk_e, topk_w);
  hist_kernel<<<R_ / 1024, 256, 0, stream>>>(topk_e, counts);
  build_tiles_kernel<<<1, 64, 0, stream>>>(counts, pbase, cursors, tile_expert, num_tiles);
  scatter_kernel<<<R_ / 256, 256, 0, stream>>>(topk_e, topk_w, pbase, cursors, prow_token, prow_w);

  for (int p = 0; p < NPH; p++) {
    int base = p * TPP;
    fc_gemm_kernel<<<dim3(H_ / BN, TPP), 256, 0, stream>>>(xbf, WtFc, bfc, prow_token,
                                                           tile_expert, num_tiles, zrow,
                                                           Hbuf, base);
    proj_gemm_kernel<<<dim3(D_ / BN, TPP), 256, 0, stream>>>(Hbuf, WtPj, bpj, prow_token,
                                                             prow_w, tile_expert, num_tiles,
                                                             out, base);
  }
}

// Round 2
// 1530.800 us; speedup vs baseline: 1.1025x; 1.1025x over previous
//
#include <hip/hip_runtime.h>
#include <hip/hip_bf16.h>
#include <math.h>

// ---------------- problem constants ----------------
#define B_       8
#define T_       2048
#define N_TOK    (B_*T_)        // 16384 tokens
#define D_       1024
#define E_       8
#define H_       4096
#define TOPK     2
#define R_       (N_TOK*TOPK)   // 32768 gathered rows
#define OUT_ELEMS ((size_t)N_TOK*D_)

// ---------------- GEMM tiling ----------------
#define BM 128
#define BN 128
#define BK 32                    // single 16.9KB-LDS panel (round-0 structure)
#define MAXT 264                 // sum_e ceil(n_e/128) <= 263; 264 safe
#define NPH 3                    // phases (Hbuf reuse to fit ws)
#define TPP 88                   // tiles per phase, 3*88 = 264
#define HROWS (TPP*BM)           // 11264 rows per phase

typedef __attribute__((ext_vector_type(8))) short short8;
typedef __attribute__((ext_vector_type(4))) float floatx4;
typedef const __attribute__((address_space(1))) void* gptr_t;
typedef __attribute__((address_space(3))) void* lptr_t;

__device__ __forceinline__ void gl16(const void* g, void* l) {
  // async global->LDS, 16B/lane; LDS dest = wave-uniform base + lane*16
  __builtin_amdgcn_global_load_lds((gptr_t)g, (lptr_t)l, 16, 0, 0);
}

__device__ __forceinline__ unsigned short f2bf(float f) {
  union { float f; unsigned int u; } v; v.f = f;
  unsigned int u = v.u;
  u += 0x7FFFu + ((u >> 16) & 1u);   // RNE
  return (unsigned short)(u >> 16);
}

// tanh-GELU via its sigmoid identity:
//   0.5v(1+tanh(u)) == v * sigmoid(2u),  2u = 1.5957691216(v + 0.044715 v^3)
// ~7 VALU ops vs ~35 for libm tanhf.
__device__ __forceinline__ float gelu_tanh(float v) {
  float u = __builtin_fmaf(v * v, -0.10294325f, -2.30220830f);
  float p = __builtin_amdgcn_exp2f(v * u);
  return v * __builtin_amdgcn_rcpf(1.0f + p);
}

// ---------------- router: one wave per token (NO global atomics) ----------------
__global__ __launch_bounds__(256) void router_kernel(
    const float* __restrict__ x, const int* __restrict__ city_idx_p,
    const float* __restrict__ dt, const float* __restrict__ dd,
    const float* __restrict__ drg, const float* __restrict__ de,
    const float* __restrict__ cemb, const float* __restrict__ Wr,
    const float* __restrict__ br,
    float* __restrict__ gate1, int* __restrict__ topk_e,
    float* __restrict__ topk_w)
{
  const int wid = threadIdx.x >> 6, lane = threadIdx.x & 63;
  const int token = blockIdx.x * 4 + wid;

  float acc[E_];
#pragma unroll
  for (int e = 0; e < E_; e++) acc[e] = 0.f;

  const float* ce = cemb + (*city_idx_p) * 32;

  // ng = number of float4 groups; lane handles groups lane, lane+64, ...
  auto fma_seg4 = [&](const float* src, int ng, int base) {
    for (int i = lane; i < ng; i += 64) {
      float4 f = ((const float4*)src)[i];
      const float4* wv = (const float4*)(Wr + (size_t)(base + i * 4) * E_);
      float4 w0 = wv[0], w1 = wv[1], w2 = wv[2], w3 = wv[3];
      float4 w4 = wv[4], w5 = wv[5], w6 = wv[6], w7 = wv[7];
      acc[0] += f.x * w0.x; acc[1] += f.x * w0.y; acc[2] += f.x * w0.z; acc[3] += f.x * w0.w;
      acc[4] += f.x * w1.x; acc[5] += f.x * w1.y; acc[6] += f.x * w1.z; acc[7] += f.x * w1.w;
      acc[0] += f.y * w2.x; acc[1] += f.y * w2.y; acc[2] += f.y * w2.z; acc[3] += f.y * w2.w;
      acc[4] += f.y * w3.x; acc[5] += f.y * w3.y; acc[6] += f.y * w3.z; acc[7] += f.y * w3.w;
      acc[0] += f.z * w4.x; acc[1] += f.z * w4.y; acc[2] += f.z * w4.z; acc[3] += f.z * w4.w;
      acc[4] += f.z * w5.x; acc[5] += f.z * w5.y; acc[6] += f.z * w5.z; acc[7] += f.z * w5.w;
      acc[0] += f.w * w6.x; acc[1] += f.w * w6.y; acc[2] += f.w * w6.z; acc[3] += f.w * w6.w;
      acc[4] += f.w * w7.x; acc[5] += f.w * w7.y; acc[6] += f.w * w7.z; acc[7] += f.w * w7.w;
    }
  };
  fma_seg4(x  + (size_t)token * D_,  D_ / 4, 0);
  fma_seg4(ce,                       32 / 4, 1024);
  fma_seg4(dt + (size_t)token * 256, 256 / 4, 1056);
  fma_seg4(dd + (size_t)token * 256, 256 / 4, 1312);
  fma_seg4(drg+ (size_t)token * 128, 128 / 4, 1568);
  fma_seg4(de + (size_t)token * 128, 128 / 4, 1696);

#pragma unroll
  for (int e = 0; e < E_; e++) {
    float v = acc[e];
#pragma unroll
    for (int s = 32; s > 0; s >>= 1) v += __shfl_xor(v, s, 64);
    acc[e] = v + br[e];
  }

  if (lane == 0) {
    float mx = acc[0];
#pragma unroll
    for (int e = 1; e < E_; e++) mx = fmaxf(mx, acc[e]);
    float s = 0.f, ex[E_];
#pragma unroll
    for (int e = 0; e < E_; e++) { ex[e] = expf(acc[e] - mx); s += ex[e]; }
    float inv = 1.f / s;
#pragma unroll
    for (int e = 0; e < E_; e++) gate1[(size_t)token * E_ + e] = ex[e] * inv;

    int e0 = 0;
#pragma unroll
    for (int e = 1; e < E_; e++) if (acc[e] > acc[e0]) e0 = e;
    int e1 = (e0 == 0) ? 1 : 0;
#pragma unroll
    for (int e = 0; e < E_; e++) if (e != e0 && acc[e] > acc[e1]) e1 = e;
    float t2 = expf(acc[e1] - acc[e0]);
    float w0 = 1.f / (1.f + t2), w1 = t2 / (1.f + t2);
    topk_e[token * 2]     = e0; topk_e[token * 2 + 1] = e1;
    topk_w[token * 2]     = w0; topk_w[token * 2 + 1] = w1;
  }
}

// ---------------- histogram: LDS bins, 8 global atomics per block ----------------
__global__ __launch_bounds__(256) void hist_kernel(const int* __restrict__ topk_e,
                                                   int* __restrict__ counts)
{
  __shared__ int h[E_];
  const int t = threadIdx.x;
  if (t < E_) h[t] = 0;
  __syncthreads();
  const int base = blockIdx.x * 1024 + t;
#pragma unroll
  for (int j = 0; j < 4; j++) atomicAdd(&h[topk_e[base + j * 256]], 1);
  __syncthreads();
  if (t < E_ && h[t] > 0) atomicAdd(&counts[t], h[t]);
}

// ---------------- build padded tile table ----------------
__global__ void build_tiles_kernel(const int* __restrict__ counts, int* pbase,
                                   int* cursors, int* tile_expert, int* num_tiles)
{
  if (threadIdx.x == 0 && blockIdx.x == 0) {
    int t = 0;
    for (int e = 0; e < E_; e++) {
      pbase[e] = t * BM;
      cursors[e] = 0;
      int nt = (counts[e] + BM - 1) / BM;
      for (int i = 0; i < nt; i++) tile_expert[t++] = e;
    }
    *num_tiles = t;
  }
}

// ---------------- scatter token->padded row (hierarchical reservation) ----------------
__global__ __launch_bounds__(256) void scatter_kernel(
    const int* __restrict__ topk_e, const float* __restrict__ topk_w,
    const int* __restrict__ pbase, int* __restrict__ cursors,
    int* __restrict__ prow_token, float* __restrict__ prow_w)
{
  __shared__ int wcnt[4][E_];
  __shared__ int wbase[4][E_];
  const int t = threadIdx.x, lane = t & 63, wid = t >> 6;
  if (t < 32) ((int*)wcnt)[t] = 0;
  __syncthreads();

  const int idx = blockIdx.x * 256 + t;
  const int e = topk_e[idx];
  const float w = topk_w[idx];

  // same-e lane mask via 3 ballots (e has 3 bits)
  unsigned long long b0 = __ballot(e & 1);
  unsigned long long b1 = __ballot(e & 2);
  unsigned long long b2 = __ballot(e & 4);
  unsigned long long m = ((e & 1) ? b0 : ~b0) & ((e & 2) ? b1 : ~b1) & ((e & 4) ? b2 : ~b2);
  unsigned long long below = ((unsigned long long)1 << lane) - 1;
  const int rank = __popcll(m & below);
  if (rank == 0) wcnt[wid][e] = __popcll(m);
  __syncthreads();

  if (t < E_) {
    int run = 0, tmp[4];
#pragma unroll
    for (int w2 = 0; w2 < 4; w2++) { tmp[w2] = run; run += wcnt[w2][t]; }
    int gb = (run > 0) ? atomicAdd(&cursors[t], run) : 0;
#pragma unroll
    for (int w2 = 0; w2 < 4; w2++) wbase[w2][t] = gb + tmp[w2];
  }
  __syncthreads();

  const int pos = pbase[e] + wbase[wid][e] + rank;
  prow_token[pos] = idx >> 1;
  prow_w[pos] = w;
}

// ---------------- x f32 -> bf16 ----------------
__global__ __launch_bounds__(256) void xconv_kernel(const float* __restrict__ x,
                                                    unsigned short* __restrict__ xbf)
{
  size_t i = ((size_t)blockIdx.x * 256 + threadIdx.x) * 8;
  float4 a = ((const float4*)(x + i))[0], b = ((const float4*)(x + i))[1];
  unsigned short o[8] = {f2bf(a.x), f2bf(a.y), f2bf(a.z), f2bf(a.w),
                         f2bf(b.x), f2bf(b.y), f2bf(b.z), f2bf(b.w)};
  *(short8*)(xbf + i) = *(short8*)o;
}

// ---------------- W [e][K][N] f32  ->  Wt [e][N][K] bf16 ----------------
__global__ __launch_bounds__(256) void wtrans_kernel(
    const float* __restrict__ W, unsigned short* __restrict__ Wt, int K, int N)
{
  const int e = blockIdx.z, k0 = blockIdx.x * 32, n0 = blockIdx.y * 128;
  __shared__ unsigned short Ls[128 * 40];   // [n][k], stride 40
  const int t = threadIdx.x;
  const int kr = t >> 3;
  const int cg = (t & 7) * 16;
  const float* src = W + ((size_t)e * K + k0 + kr) * N + n0 + cg;
  float4 f0 = ((const float4*)src)[0];
  float4 f1 = ((const float4*)src)[1];
  float4 f2 = ((const float4*)src)[2];
  float4 f3 = ((const float4*)src)[3];
  float v[16] = {f0.x,f0.y,f0.z,f0.w, f1.x,f1.y,f1.z,f1.w,
                 f2.x,f2.y,f2.z,f2.w, f3.x,f3.y,f3.z,f3.w};
#pragma unroll
  for (int j = 0; j < 16; j++) Ls[(cg + j) * 40 + kr] = f2bf(v[j]);
  __syncthreads();
  const int r = t >> 1, hh = (t & 1) * 16;
  unsigned short* dst = Wt + ((size_t)e * N + n0 + r) * K + k0 + hh;
  short8 o0 = *(short8*)&Ls[r * 40 + hh];
  short8 o1 = *(short8*)&Ls[r * 40 + hh + 8];
  *(short8*)dst       = o0;
  *(short8*)(dst + 8) = o1;
}

// ---------------- GEMM1: H = gelu(Xg @ Wfc[e] + bfc[e]) ----------------
// grid (32, TPP); XCD-swizzled so all 32 blocks sharing an A-tile sit on one XCD's L2
__global__ __launch_bounds__(256) void fc_gemm_kernel(
    const unsigned short* __restrict__ xbf, const unsigned short* __restrict__ Wt,
    const float* __restrict__ bfc, const int* __restrict__ prow_token,
    const int* __restrict__ tile_expert, const int* __restrict__ num_tiles_p,
    const unsigned short* __restrict__ zrow,
    unsigned short* __restrict__ H, int tile_base)
{
  // bijective XCD swizzle: nwg = 32*TPP = 2816, per-XCD chunk = 352
  const int s  = blockIdx.y * 32 + blockIdx.x;
  const int w  = (s & 7) * ((32 * TPP) >> 3) + (s >> 3);
  const int bx = w & 31;
  const int by = w >> 5;

  const int tile = tile_base + by;
  if (tile >= *num_tiles_p) return;
  const int e  = tile_expert[tile];
  const int n0 = bx * BN;
  const int ltile = tile - tile_base;

  __shared__ unsigned short As[BM * BK];   // [row][k], stride 32 (m97 layout)
  __shared__ unsigned short Bs[BN * BK];
  __shared__ int toks[BM];

  const int t = threadIdx.x;
  if (t < BM) toks[t] = prow_token[tile * BM + t];
  __syncthreads();

  const int lane = t & 63, wid = t >> 6;
  const int ko = (lane & 3) * 8;
  const int r0 = wid * 32 + (lane >> 2);
  const int tk0 = toks[r0], tk1 = toks[r0 + 16];
  const unsigned short* pa0 = (tk0 >= 0) ? xbf + (size_t)tk0 * D_ + ko : zrow + ko;
  const unsigned short* pa1 = (tk1 >= 0) ? xbf + (size_t)tk1 * D_ + ko : zrow + ko;
  const unsigned short* WtE = Wt + (size_t)e * H_ * D_;
  const unsigned short* pb0 = WtE + (size_t)(n0 + r0) * D_ + ko;
  const unsigned short* pb1 = pb0 + (size_t)16 * D_;
  unsigned short* lA0 = &As[wid * 1024];
  unsigned short* lA1 = &As[wid * 1024 + 512];
  unsigned short* lB0 = &Bs[wid * 1024];
  unsigned short* lB1 = &Bs[wid * 1024 + 512];

  const int wm = (wid >> 1) * 64, wn = (wid & 1) * 64;
  const int lrow = lane & 15, quad = lane >> 4;

  floatx4 acc[4][4];
#pragma unroll
  for (int i = 0; i < 4; i++)
#pragma unroll
    for (int j = 0; j < 4; j++) acc[i][j] = (floatx4){0.f, 0.f, 0.f, 0.f};

  for (int k0 = 0; k0 < D_; k0 += BK) {
    gl16(pa0 + k0, lA0);
    gl16(pa1 + k0, lA1);
    gl16(pb0 + k0, lB0);
    gl16(pb1 + k0, lB1);
    __syncthreads();

    short8 af[4], bfr[4];
#pragma unroll
    for (int mi = 0; mi < 4; mi++)
      af[mi]  = *(const short8*)&As[(wm + mi * 16 + lrow) * BK + quad * 8];
#pragma unroll
    for (int ni = 0; ni < 4; ni++)
      bfr[ni] = *(const short8*)&Bs[(wn + ni * 16 + lrow) * BK + quad * 8];
#pragma unroll
    for (int mi = 0; mi < 4; mi++)
#pragma unroll
      for (int ni = 0; ni < 4; ni++)
        acc[mi][ni] = __builtin_amdgcn_mfma_f32_16x16x32_bf16(af[mi], bfr[ni], acc[mi][ni], 0, 0, 0);
    __syncthreads();
  }

  const float* bias = bfc + (size_t)e * H_ + n0;
#pragma unroll
  for (int mi = 0; mi < 4; mi++) {
    int row = wm + mi * 16 + quad * 4;
#pragma unroll
    for (int ni = 0; ni < 4; ni++) {
      int col = wn + ni * 16 + lrow;
      float b = bias[col];
#pragma unroll
      for (int r = 0; r < 4; r++) {
        float v = acc[mi][ni][r] + b;
        H[(size_t)(ltile * BM + row + r) * H_ + n0 + col] = f2bf(gelu_tanh(v));
      }
    }
  }
}

// ---------------- GEMM2: out += w * (H @ Wproj[e] + bproj[e]) ----------------
// grid (8, TPP, 2): split-K over blockIdx.z (atomicAdd epilogue is accumulation-safe);
// XCD-swizzled like fc.
__global__ __launch_bounds__(256) void proj_gemm_kernel(
    const unsigned short* __restrict__ H, const unsigned short* __restrict__ Wt,
    const float* __restrict__ bpj, const int* __restrict__ prow_token,
    const float* __restrict__ prow_w, const int* __restrict__ tile_expert,
    const int* __restrict__ num_tiles_p, float* __restrict__ out, int tile_base)
{
  // bijective swizzle over the full 3D grid: nwg = 8*TPP*2 = 1408, chunk = 176
  const int s  = blockIdx.x + (blockIdx.y << 3) + blockIdx.z * (8 * TPP);
  const int w  = (s & 7) * ((8 * TPP * 2) >> 3) + (s >> 3);
  const int z  = (w >= 8 * TPP) ? 1 : 0;
  const int rem = w - z * (8 * TPP);
  const int bx = rem & 7;
  const int by = rem >> 3;

  const int tile = tile_base + by;
  if (tile >= *num_tiles_p) return;
  const int e  = tile_expert[tile];
  const int n0 = bx * BN;
  const int ltile = tile - tile_base;

  __shared__ unsigned short As[BM * BK];
  __shared__ unsigned short Bs[BN * BK];
  __shared__ int   toks[BM];
  __shared__ float wgt[BM];

  const int t = threadIdx.x;
  if (t < BM) { toks[t] = prow_token[tile * BM + t]; wgt[t] = prow_w[tile * BM + t]; }
  __syncthreads();

  const int lane = t & 63, wid = t >> 6;
  const int ko = (lane & 3) * 8;
  const int r0 = wid * 32 + (lane >> 2);
  const unsigned short* pa0 = H + (size_t)(ltile * BM + r0) * H_ + ko;
  const unsigned short* pa1 = pa0 + (size_t)16 * H_;
  const unsigned short* WtE = Wt + (size_t)e * D_ * H_;
  const unsigned short* pb0 = WtE + (size_t)(n0 + r0) * H_ + ko;
  const unsigned short* pb1 = pb0 + (size_t)16 * H_;
  unsigned short* lA0 = &As[wid * 1024];
  unsigned short* lA1 = &As[wid * 1024 + 512];
  unsigned short* lB0 = &Bs[wid * 1024];
  unsigned short* lB1 = &Bs[wid * 1024 + 512];

  const int wm = (wid >> 1) * 64, wn = (wid & 1) * 64;
  const int lrow = lane & 15, quad = lane >> 4;

  floatx4 acc[4][4];
#pragma unroll
  for (int i = 0; i < 4; i++)
#pragma unroll
    for (int j = 0; j < 4; j++) acc[i][j] = (floatx4){0.f, 0.f, 0.f, 0.f};

  const int kbeg = z * (H_ / 2), kend = kbeg + (H_ / 2);
  for (int k0 = kbeg; k0 < kend; k0 += BK) {
    gl16(pa0 + k0, lA0);
    gl16(pa1 + k0, lA1);
    gl16(pb0 + k0, lB0);
    gl16(pb1 + k0, lB1);
    __syncthreads();

    short8 af[4], bfr[4];
#pragma unroll
    for (int mi = 0; mi < 4; mi++)
      af[mi]  = *(const short8*)&As[(wm + mi * 16 + lrow) * BK + quad * 8];
#pragma unroll
    for (int ni = 0; ni < 4; ni++)
      bfr[ni] = *(const short8*)&Bs[(wn + ni * 16 + lrow) * BK + quad * 8];
#pragma unroll
    for (int mi = 0; mi < 4; mi++)
#pragma unroll
      for (int ni = 0; ni < 4; ni++)
        acc[mi][ni] = __builtin_amdgcn_mfma_f32_16x16x32_bf16(af[mi], bfr[ni], acc[mi][ni], 0, 0, 0);
    __syncthreads();
  }

  const float* bias = bpj + (size_t)e * D_ + n0;
#pragma unroll
  for (int mi = 0; mi < 4; mi++) {
    int row = wm + mi * 16 + quad * 4;
#pragma unroll
    for (int ni = 0; ni < 4; ni++) {
      int col = wn + ni * 16 + lrow;
      float b = z ? 0.f : bias[col];
#pragma unroll
      for (int r = 0; r < 4; r++) {
        int rr = row + r;
        int tok = toks[rr];
        if (tok >= 0) {
          float v = (acc[mi][ni][r] + b) * wgt[rr];
          atomicAdd(&out[(size_t)tok * D_ + n0 + col], v);
        }
      }
    }
  }
}

// ---------------- host launcher ----------------
extern "C" void kernel_launch(void* const* d_in, const int* in_sizes, int n_in,
                              void* d_out, int out_size, void* d_ws, size_t ws_size,
                              hipStream_t stream)
{
  const float* x    = (const float*)d_in[0];
  const int*   cidx = (const int*)d_in[1];
  const float* dt   = (const float*)d_in[2];
  const float* dd   = (const float*)d_in[3];
  const float* drg  = (const float*)d_in[4];
  const float* de   = (const float*)d_in[5];
  const float* cemb = (const float*)d_in[6];
  const float* Wr   = (const float*)d_in[7];
  const float* br   = (const float*)d_in[8];
  const float* Wfc  = (const float*)d_in[9];
  const float* bfc  = (const float*)d_in[10];
  const float* Wpj  = (const float*)d_in[11];
  const float* bpj  = (const float*)d_in[12];

  float* out   = (float*)d_out;
  float* gate1 = out + OUT_ELEMS;

  char* ws = (char*)d_ws;
  size_t off = 0;
  auto take = [&](size_t bytes) { size_t r = off; off += (bytes + 255) & ~(size_t)255; return r; };
  unsigned short* Hbuf  = (unsigned short*)(ws + take((size_t)HROWS * H_ * 2));   // 92.3 MB
  unsigned short* xbf   = (unsigned short*)(ws + take((size_t)N_TOK * D_ * 2));   // 33.6 MB
  unsigned short* WtFc  = (unsigned short*)(ws + take((size_t)E_ * H_ * D_ * 2)); // 67.1 MB
  unsigned short* WtPj  = (unsigned short*)(ws + take((size_t)E_ * D_ * H_ * 2)); // 67.1 MB
  int*   topk_e      = (int*)  (ws + take((size_t)R_ * 4));
  float* topk_w      = (float*)(ws + take((size_t)R_ * 4));
  int*   prow_token  = (int*)  (ws + take((size_t)(MAXT * BM) * 4));
  float* prow_w      = (float*)(ws + take((size_t)(MAXT * BM) * 4));
  unsigned short* zrow = (unsigned short*)(ws + take(4096));
  int*   counts      = (int*)  (ws + take(E_ * 4));
  int*   cursors     = (int*)  (ws + take(E_ * 4));
  int*   pbase       = (int*)  (ws + take(E_ * 4));
  int*   tile_expert = (int*)  (ws + take(MAXT * 4));
  int*   num_tiles   = (int*)  (ws + take(4));
  (void)ws_size; (void)in_sizes; (void)n_in; (void)out_size;

  hipMemsetAsync(d_out, 0, OUT_ELEMS * 4, stream);
  hipMemsetAsync(counts, 0, E_ * 4, stream);
  hipMemsetAsync(prow_token, 0xFF, (size_t)(MAXT * BM) * 4, stream);
  hipMemsetAsync(zrow, 0, 4096, stream);

  xconv_kernel<<<(N_TOK * D_) / (256 * 8), 256, 0, stream>>>(x, xbf);
  wtrans_kernel<<<dim3(D_ / 32, H_ / 128, E_), 256, 0, stream>>>(Wfc, WtFc, D_, H_);
  wtrans_kernel<<<dim3(H_ / 32, D_ / 128, E_), 256, 0, stream>>>(Wpj, WtPj, H_, D_);

  router_kernel<<<N_TOK / 4, 256, 0, stream>>>(x, cidx, dt, dd, drg, de, cemb, Wr, br,
                                               gate1, topk_e, topk_w);
  hist_kernel<<<R_ / 1024, 256, 0, stream>>>(topk_e, counts);
  build_tiles_kernel<<<1, 64, 0, stream>>>(counts, pbase, cursors, tile_expert, num_tiles);
  scatter_kernel<<<R_ / 256, 256, 0, stream>>>(topk_e, topk_w, pbase, cursors, prow_token, prow_w);

  for (int p = 0; p < NPH; p++) {
    int base = p * TPP;
    fc_gemm_kernel<<<dim3(H_ / BN, TPP), 256, 0, stream>>>(xbf, WtFc, bfc, prow_token,
                                                           tile_expert, num_tiles, zrow,
                                                           Hbuf, base);
    proj_gemm_kernel<<<dim3(D_ / BN, TPP, 2), 256, 0, stream>>>(Hbuf, WtPj, bpj, prow_token,
                                                                prow_w, tile_expert, num_tiles,
                                                                out, base);
  }
}

// Round 3
// 1369.589 us; speedup vs baseline: 1.2322x; 1.1177x over previous
//
#include <hip/hip_runtime.h>
#include <hip/hip_bf16.h>
#include <math.h>

// ---------------- problem constants ----------------
#define B_       8
#define T_       2048
#define N_TOK    (B_*T_)        // 16384 tokens
#define D_       1024
#define E_       8
#define H_       4096
#define TOPK     2
#define R_       (N_TOK*TOPK)   // 32768 gathered rows
#define OUT_ELEMS ((size_t)N_TOK*D_)

// ---------------- GEMM tiling ----------------
#define BM 128
#define BN 128
#define BK 32                    // single 16.9KB-LDS panel (round-0 structure)
#define MAXT 264                 // sum_e ceil(n_e/128) <= 263; 264 safe
#define NPH 3                    // phases (Hbuf reuse to fit ws)
#define TPP 88                   // tiles per phase, 3*88 = 264
#define HROWS (TPP*BM)           // 11264 rows per phase

typedef __attribute__((ext_vector_type(8))) short short8;
typedef __attribute__((ext_vector_type(4))) float floatx4;
typedef const __attribute__((address_space(1))) void* gptr_t;
typedef __attribute__((address_space(3))) void* lptr_t;

__device__ __forceinline__ void gl16(const void* g, void* l) {
  // async global->LDS, 16B/lane; LDS dest = wave-uniform base + lane*16
  __builtin_amdgcn_global_load_lds((gptr_t)g, (lptr_t)l, 16, 0, 0);
}

__device__ __forceinline__ unsigned short f2bf(float f) {
  union { float f; unsigned int u; } v; v.f = f;
  unsigned int u = v.u;
  u += 0x7FFFu + ((u >> 16) & 1u);   // RNE
  return (unsigned short)(u >> 16);
}

// tanh-GELU via its sigmoid identity:
//   0.5v(1+tanh(u)) == v * sigmoid(2u),  2u = 1.5957691216(v + 0.044715 v^3)
// ~7 VALU ops vs ~35 for libm tanhf. absmax bit-identical across rounds.
__device__ __forceinline__ float gelu_tanh(float v) {
  float u = __builtin_fmaf(v * v, -0.10294325f, -2.30220830f);
  float p = __builtin_amdgcn_exp2f(v * u);
  return v * __builtin_amdgcn_rcpf(1.0f + p);
}

// ---------------- router: one wave per token (NO global atomics) ----------------
__global__ __launch_bounds__(256) void router_kernel(
    const float* __restrict__ x, const int* __restrict__ city_idx_p,
    const float* __restrict__ dt, const float* __restrict__ dd,
    const float* __restrict__ drg, const float* __restrict__ de,
    const float* __restrict__ cemb, const float* __restrict__ Wr,
    const float* __restrict__ br,
    float* __restrict__ gate1, int* __restrict__ topk_e,
    float* __restrict__ topk_w)
{
  const int wid = threadIdx.x >> 6, lane = threadIdx.x & 63;
  const int token = blockIdx.x * 4 + wid;

  float acc[E_];
#pragma unroll
  for (int e = 0; e < E_; e++) acc[e] = 0.f;

  const float* ce = cemb + (*city_idx_p) * 32;

  // ng = number of float4 groups; lane handles groups lane, lane+64, ...
  auto fma_seg4 = [&](const float* src, int ng, int base) {
    for (int i = lane; i < ng; i += 64) {
      float4 f = ((const float4*)src)[i];
      const float4* wv = (const float4*)(Wr + (size_t)(base + i * 4) * E_);
      float4 w0 = wv[0], w1 = wv[1], w2 = wv[2], w3 = wv[3];
      float4 w4 = wv[4], w5 = wv[5], w6 = wv[6], w7 = wv[7];
      acc[0] += f.x * w0.x; acc[1] += f.x * w0.y; acc[2] += f.x * w0.z; acc[3] += f.x * w0.w;
      acc[4] += f.x * w1.x; acc[5] += f.x * w1.y; acc[6] += f.x * w1.z; acc[7] += f.x * w1.w;
      acc[0] += f.y * w2.x; acc[1] += f.y * w2.y; acc[2] += f.y * w2.z; acc[3] += f.y * w2.w;
      acc[4] += f.y * w3.x; acc[5] += f.y * w3.y; acc[6] += f.y * w3.z; acc[7] += f.y * w3.w;
      acc[0] += f.z * w4.x; acc[1] += f.z * w4.y; acc[2] += f.z * w4.z; acc[3] += f.z * w4.w;
      acc[4] += f.z * w5.x; acc[5] += f.z * w5.y; acc[6] += f.z * w5.z; acc[7] += f.z * w5.w;
      acc[0] += f.w * w6.x; acc[1] += f.w * w6.y; acc[2] += f.w * w6.z; acc[3] += f.w * w6.w;
      acc[4] += f.w * w7.x; acc[5] += f.w * w7.y; acc[6] += f.w * w7.z; acc[7] += f.w * w7.w;
    }
  };
  fma_seg4(x  + (size_t)token * D_,  D_ / 4, 0);
  fma_seg4(ce,                       32 / 4, 1024);
  fma_seg4(dt + (size_t)token * 256, 256 / 4, 1056);
  fma_seg4(dd + (size_t)token * 256, 256 / 4, 1312);
  fma_seg4(drg+ (size_t)token * 128, 128 / 4, 1568);
  fma_seg4(de + (size_t)token * 128, 128 / 4, 1696);

#pragma unroll
  for (int e = 0; e < E_; e++) {
    float v = acc[e];
#pragma unroll
    for (int s = 32; s > 0; s >>= 1) v += __shfl_xor(v, s, 64);
    acc[e] = v + br[e];
  }

  if (lane == 0) {
    float mx = acc[0];
#pragma unroll
    for (int e = 1; e < E_; e++) mx = fmaxf(mx, acc[e]);
    float s = 0.f, ex[E_];
#pragma unroll
    for (int e = 0; e < E_; e++) { ex[e] = expf(acc[e] - mx); s += ex[e]; }
    float inv = 1.f / s;
#pragma unroll
    for (int e = 0; e < E_; e++) gate1[(size_t)token * E_ + e] = ex[e] * inv;

    int e0 = 0;
#pragma unroll
    for (int e = 1; e < E_; e++) if (acc[e] > acc[e0]) e0 = e;
    int e1 = (e0 == 0) ? 1 : 0;
#pragma unroll
    for (int e = 0; e < E_; e++) if (e != e0 && acc[e] > acc[e1]) e1 = e;
    float t2 = expf(acc[e1] - acc[e0]);
    float w0 = 1.f / (1.f + t2), w1 = t2 / (1.f + t2);
    topk_e[token * 2]     = e0; topk_e[token * 2 + 1] = e1;
    topk_w[token * 2]     = w0; topk_w[token * 2 + 1] = w1;
  }
}

// ---------------- histogram: LDS bins, 8 global atomics per block ----------------
__global__ __launch_bounds__(256) void hist_kernel(const int* __restrict__ topk_e,
                                                   int* __restrict__ counts)
{
  __shared__ int h[E_];
  const int t = threadIdx.x;
  if (t < E_) h[t] = 0;
  __syncthreads();
  const int base = blockIdx.x * 1024 + t;
#pragma unroll
  for (int j = 0; j < 4; j++) atomicAdd(&h[topk_e[base + j * 256]], 1);
  __syncthreads();
  if (t < E_ && h[t] > 0) atomicAdd(&counts[t], h[t]);
}

// ---------------- build padded tile table ----------------
__global__ void build_tiles_kernel(const int* __restrict__ counts, int* pbase,
                                   int* cursors, int* tile_expert, int* num_tiles)
{
  if (threadIdx.x == 0 && blockIdx.x == 0) {
    int t = 0;
    for (int e = 0; e < E_; e++) {
      pbase[e] = t * BM;
      cursors[e] = 0;
      int nt = (counts[e] + BM - 1) / BM;
      for (int i = 0; i < nt; i++) tile_expert[t++] = e;
    }
    *num_tiles = t;
  }
}

// ---------------- scatter token->padded row (hierarchical reservation) ----------------
__global__ __launch_bounds__(256) void scatter_kernel(
    const int* __restrict__ topk_e, const float* __restrict__ topk_w,
    const int* __restrict__ pbase, int* __restrict__ cursors,
    int* __restrict__ prow_token, float* __restrict__ prow_w)
{
  __shared__ int wcnt[4][E_];
  __shared__ int wbase[4][E_];
  const int t = threadIdx.x, lane = t & 63, wid = t >> 6;
  if (t < 32) ((int*)wcnt)[t] = 0;
  __syncthreads();

  const int idx = blockIdx.x * 256 + t;
  const int e = topk_e[idx];
  const float w = topk_w[idx];

  // same-e lane mask via 3 ballots (e has 3 bits)
  unsigned long long b0 = __ballot(e & 1);
  unsigned long long b1 = __ballot(e & 2);
  unsigned long long b2 = __ballot(e & 4);
  unsigned long long m = ((e & 1) ? b0 : ~b0) & ((e & 2) ? b1 : ~b1) & ((e & 4) ? b2 : ~b2);
  unsigned long long below = ((unsigned long long)1 << lane) - 1;
  const int rank = __popcll(m & below);
  if (rank == 0) wcnt[wid][e] = __popcll(m);
  __syncthreads();

  if (t < E_) {
    int run = 0, tmp[4];
#pragma unroll
    for (int w2 = 0; w2 < 4; w2++) { tmp[w2] = run; run += wcnt[w2][t]; }
    int gb = (run > 0) ? atomicAdd(&cursors[t], run) : 0;
#pragma unroll
    for (int w2 = 0; w2 < 4; w2++) wbase[w2][t] = gb + tmp[w2];
  }
  __syncthreads();

  const int pos = pbase[e] + wbase[wid][e] + rank;
  prow_token[pos] = idx >> 1;
  prow_w[pos] = w;
}

// ---------------- x f32 -> bf16 ----------------
__global__ __launch_bounds__(256) void xconv_kernel(const float* __restrict__ x,
                                                    unsigned short* __restrict__ xbf)
{
  size_t i = ((size_t)blockIdx.x * 256 + threadIdx.x) * 8;
  float4 a = ((const float4*)(x + i))[0], b = ((const float4*)(x + i))[1];
  unsigned short o[8] = {f2bf(a.x), f2bf(a.y), f2bf(a.z), f2bf(a.w),
                         f2bf(b.x), f2bf(b.y), f2bf(b.z), f2bf(b.w)};
  *(short8*)(xbf + i) = *(short8*)o;
}

// ---------------- W [e][K][N] f32  ->  Wt [e][N][K] bf16 ----------------
__global__ __launch_bounds__(256) void wtrans_kernel(
    const float* __restrict__ W, unsigned short* __restrict__ Wt, int K, int N)
{
  const int e = blockIdx.z, k0 = blockIdx.x * 32, n0 = blockIdx.y * 128;
  __shared__ unsigned short Ls[128 * 40];   // [n][k], stride 40
  const int t = threadIdx.x;
  const int kr = t >> 3;
  const int cg = (t & 7) * 16;
  const float* src = W + ((size_t)e * K + k0 + kr) * N + n0 + cg;
  float4 f0 = ((const float4*)src)[0];
  float4 f1 = ((const float4*)src)[1];
  float4 f2 = ((const float4*)src)[2];
  float4 f3 = ((const float4*)src)[3];
  float v[16] = {f0.x,f0.y,f0.z,f0.w, f1.x,f1.y,f1.z,f1.w,
                 f2.x,f2.y,f2.z,f2.w, f3.x,f3.y,f3.z,f3.w};
#pragma unroll
  for (int j = 0; j < 16; j++) Ls[(cg + j) * 40 + kr] = f2bf(v[j]);
  __syncthreads();
  const int r = t >> 1, hh = (t & 1) * 16;
  unsigned short* dst = Wt + ((size_t)e * N + n0 + r) * K + k0 + hh;
  short8 o0 = *(short8*)&Ls[r * 40 + hh];
  short8 o1 = *(short8*)&Ls[r * 40 + hh + 8];
  *(short8*)dst       = o0;
  *(short8*)(dst + 8) = o1;
}

// ---------------- GEMM1: H = gelu(Xg @ Wfc[e] + bfc[e]) ----------------
// round-0 structure: plain dispatch order (no swizzle) + cheap GELU epilogue
__global__ __launch_bounds__(256) void fc_gemm_kernel(
    const unsigned short* __restrict__ xbf, const unsigned short* __restrict__ Wt,
    const float* __restrict__ bfc, const int* __restrict__ prow_token,
    const int* __restrict__ tile_expert, const int* __restrict__ num_tiles_p,
    const unsigned short* __restrict__ zrow,
    unsigned short* __restrict__ H, int tile_base)
{
  const int tile = tile_base + blockIdx.y;
  if (tile >= *num_tiles_p) return;
  const int e  = tile_expert[tile];
  const int n0 = blockIdx.x * BN;
  const int ltile = tile - tile_base;

  __shared__ unsigned short As[BM * BK];   // [row][k], stride 32 (m97 layout)
  __shared__ unsigned short Bs[BN * BK];
  __shared__ int toks[BM];

  const int t = threadIdx.x;
  if (t < BM) toks[t] = prow_token[tile * BM + t];
  __syncthreads();

  const int lane = t & 63, wid = t >> 6;
  const int ko = (lane & 3) * 8;
  const int r0 = wid * 32 + (lane >> 2);
  const int tk0 = toks[r0], tk1 = toks[r0 + 16];
  const unsigned short* pa0 = (tk0 >= 0) ? xbf + (size_t)tk0 * D_ + ko : zrow + ko;
  const unsigned short* pa1 = (tk1 >= 0) ? xbf + (size_t)tk1 * D_ + ko : zrow + ko;
  const unsigned short* WtE = Wt + (size_t)e * H_ * D_;
  const unsigned short* pb0 = WtE + (size_t)(n0 + r0) * D_ + ko;
  const unsigned short* pb1 = pb0 + (size_t)16 * D_;
  unsigned short* lA0 = &As[wid * 1024];
  unsigned short* lA1 = &As[wid * 1024 + 512];
  unsigned short* lB0 = &Bs[wid * 1024];
  unsigned short* lB1 = &Bs[wid * 1024 + 512];

  const int wm = (wid >> 1) * 64, wn = (wid & 1) * 64;
  const int lrow = lane & 15, quad = lane >> 4;

  floatx4 acc[4][4];
#pragma unroll
  for (int i = 0; i < 4; i++)
#pragma unroll
    for (int j = 0; j < 4; j++) acc[i][j] = (floatx4){0.f, 0.f, 0.f, 0.f};

  for (int k0 = 0; k0 < D_; k0 += BK) {
    gl16(pa0 + k0, lA0);
    gl16(pa1 + k0, lA1);
    gl16(pb0 + k0, lB0);
    gl16(pb1 + k0, lB1);
    __syncthreads();

    short8 af[4], bfr[4];
#pragma unroll
    for (int mi = 0; mi < 4; mi++)
      af[mi]  = *(const short8*)&As[(wm + mi * 16 + lrow) * BK + quad * 8];
#pragma unroll
    for (int ni = 0; ni < 4; ni++)
      bfr[ni] = *(const short8*)&Bs[(wn + ni * 16 + lrow) * BK + quad * 8];
#pragma unroll
    for (int mi = 0; mi < 4; mi++)
#pragma unroll
      for (int ni = 0; ni < 4; ni++)
        acc[mi][ni] = __builtin_amdgcn_mfma_f32_16x16x32_bf16(af[mi], bfr[ni], acc[mi][ni], 0, 0, 0);
    __syncthreads();
  }

  const float* bias = bfc + (size_t)e * H_ + n0;
#pragma unroll
  for (int mi = 0; mi < 4; mi++) {
    int row = wm + mi * 16 + quad * 4;
#pragma unroll
    for (int ni = 0; ni < 4; ni++) {
      int col = wn + ni * 16 + lrow;
      float b = bias[col];
#pragma unroll
      for (int r = 0; r < 4; r++) {
        float v = acc[mi][ni][r] + b;
        H[(size_t)(ltile * BM + row + r) * H_ + n0 + col] = f2bf(gelu_tanh(v));
      }
    }
  }
}

// ---------------- GEMM2: out += w * (H @ Wproj[e] + bproj[e]) ----------------
// round-0 structure (no split-K) + XCD swizzle (FETCH 378->88MB measured)
__global__ __launch_bounds__(256) void proj_gemm_kernel(
    const unsigned short* __restrict__ H, const unsigned short* __restrict__ Wt,
    const float* __restrict__ bpj, const int* __restrict__ prow_token,
    const float* __restrict__ prow_w, const int* __restrict__ tile_expert,
    const int* __restrict__ num_tiles_p, float* __restrict__ out, int tile_base)
{
  // bijective XCD swizzle: nwg = 8*TPP = 704, chunk = 88
  const int s  = blockIdx.y * 8 + blockIdx.x;
  const int w  = (s & 7) * ((8 * TPP) >> 3) + (s >> 3);
  const int bx = w & 7;
  const int by = w >> 3;

  const int tile = tile_base + by;
  if (tile >= *num_tiles_p) return;
  const int e  = tile_expert[tile];
  const int n0 = bx * BN;
  const int ltile = tile - tile_base;

  __shared__ unsigned short As[BM * BK];
  __shared__ unsigned short Bs[BN * BK];
  __shared__ int   toks[BM];
  __shared__ float wgt[BM];

  const int t = threadIdx.x;
  if (t < BM) { toks[t] = prow_token[tile * BM + t]; wgt[t] = prow_w[tile * BM + t]; }
  __syncthreads();

  const int lane = t & 63, wid = t >> 6;
  const int ko = (lane & 3) * 8;
  const int r0 = wid * 32 + (lane >> 2);
  const unsigned short* pa0 = H + (size_t)(ltile * BM + r0) * H_ + ko;
  const unsigned short* pa1 = pa0 + (size_t)16 * H_;
  const unsigned short* WtE = Wt + (size_t)e * D_ * H_;
  const unsigned short* pb0 = WtE + (size_t)(n0 + r0) * H_ + ko;
  const unsigned short* pb1 = pb0 + (size_t)16 * H_;
  unsigned short* lA0 = &As[wid * 1024];
  unsigned short* lA1 = &As[wid * 1024 + 512];
  unsigned short* lB0 = &Bs[wid * 1024];
  unsigned short* lB1 = &Bs[wid * 1024 + 512];

  const int wm = (wid >> 1) * 64, wn = (wid & 1) * 64;
  const int lrow = lane & 15, quad = lane >> 4;

  floatx4 acc[4][4];
#pragma unroll
  for (int i = 0; i < 4; i++)
#pragma unroll
    for (int j = 0; j < 4; j++) acc[i][j] = (floatx4){0.f, 0.f, 0.f, 0.f};

  for (int k0 = 0; k0 < H_; k0 += BK) {
    gl16(pa0 + k0, lA0);
    gl16(pa1 + k0, lA1);
    gl16(pb0 + k0, lB0);
    gl16(pb1 + k0, lB1);
    __syncthreads();

    short8 af[4], bfr[4];
#pragma unroll
    for (int mi = 0; mi < 4; mi++)
      af[mi]  = *(const short8*)&As[(wm + mi * 16 + lrow) * BK + quad * 8];
#pragma unroll
    for (int ni = 0; ni < 4; ni++)
      bfr[ni] = *(const short8*)&Bs[(wn + ni * 16 + lrow) * BK + quad * 8];
#pragma unroll
    for (int mi = 0; mi < 4; mi++)
#pragma unroll
      for (int ni = 0; ni < 4; ni++)
        acc[mi][ni] = __builtin_amdgcn_mfma_f32_16x16x32_bf16(af[mi], bfr[ni], acc[mi][ni], 0, 0, 0);
    __syncthreads();
  }

  const float* bias = bpj + (size_t)e * D_ + n0;
#pragma unroll
  for (int mi = 0; mi < 4; mi++) {
    int row = wm + mi * 16 + quad * 4;
#pragma unroll
    for (int ni = 0; ni < 4; ni++) {
      int col = wn + ni * 16 + lrow;
      float b = bias[col];
#pragma unroll
      for (int r = 0; r < 4; r++) {
        int rr = row + r;
        int tok = toks[rr];
        if (tok >= 0) {
          float v = (acc[mi][ni][r] + b) * wgt[rr];
          atomicAdd(&out[(size_t)tok * D_ + n0 + col], v);
        }
      }
    }
  }
}

// ---------------- host launcher ----------------
extern "C" void kernel_launch(void* const* d_in, const int* in_sizes, int n_in,
                              void* d_out, int out_size, void* d_ws, size_t ws_size,
                              hipStream_t stream)
{
  const float* x    = (const float*)d_in[0];
  const int*   cidx = (const int*)d_in[1];
  const float* dt   = (const float*)d_in[2];
  const float* dd   = (const float*)d_in[3];
  const float* drg  = (const float*)d_in[4];
  const float* de   = (const float*)d_in[5];
  const float* cemb = (const float*)d_in[6];
  const float* Wr   = (const float*)d_in[7];
  const float* br   = (const float*)d_in[8];
  const float* Wfc  = (const float*)d_in[9];
  const float* bfc  = (const float*)d_in[10];
  const float* Wpj  = (const float*)d_in[11];
  const float* bpj  = (const float*)d_in[12];

  float* out   = (float*)d_out;
  float* gate1 = out + OUT_ELEMS;

  char* ws = (char*)d_ws;
  size_t off = 0;
  auto take = [&](size_t bytes) { size_t r = off; off += (bytes + 255) & ~(size_t)255; return r; };
  unsigned short* Hbuf  = (unsigned short*)(ws + take((size_t)HROWS * H_ * 2));   // 92.3 MB
  unsigned short* xbf   = (unsigned short*)(ws + take((size_t)N_TOK * D_ * 2));   // 33.6 MB
  unsigned short* WtFc  = (unsigned short*)(ws + take((size_t)E_ * H_ * D_ * 2)); // 67.1 MB
  unsigned short* WtPj  = (unsigned short*)(ws + take((size_t)E_ * D_ * H_ * 2)); // 67.1 MB
  int*   topk_e      = (int*)  (ws + take((size_t)R_ * 4));
  float* topk_w      = (float*)(ws + take((size_t)R_ * 4));
  int*   prow_token  = (int*)  (ws + take((size_t)(MAXT * BM) * 4));
  float* prow_w      = (float*)(ws + take((size_t)(MAXT * BM) * 4));
  unsigned short* zrow = (unsigned short*)(ws + take(4096));
  int*   counts      = (int*)  (ws + take(E_ * 4));
  int*   cursors     = (int*)  (ws + take(E_ * 4));
  int*   pbase       = (int*)  (ws + take(E_ * 4));
  int*   tile_expert = (int*)  (ws + take(MAXT * 4));
  int*   num_tiles   = (int*)  (ws + take(4));
  (void)ws_size; (void)in_sizes; (void)n_in; (void)out_size;

  hipMemsetAsync(d_out, 0, OUT_ELEMS * 4, stream);
  hipMemsetAsync(counts, 0, E_ * 4, stream);
  hipMemsetAsync(prow_token, 0xFF, (size_t)(MAXT * BM) * 4, stream);
  hipMemsetAsync(zrow, 0, 4096, stream);

  xconv_kernel<<<(N_TOK * D_) / (256 * 8), 256, 0, stream>>>(x, xbf);
  wtrans_kernel<<<dim3(D_ / 32, H_ / 128, E_), 256, 0, stream>>>(Wfc, WtFc, D_, H_);
  wtrans_kernel<<<dim3(H_ / 32, D_ / 128, E_), 256, 0, stream>>>(Wpj, WtPj, H_, D_);

  router_kernel<<<N_TOK / 4, 256, 0, stream>>>(x, cidx, dt, dd, drg, de, cemb, Wr, br,
                                               gate1, topk_e, topk_w);
  hist_kernel<<<R_ / 1024, 256, 0, stream>>>(topk_e, counts);
  build_tiles_kernel<<<1, 64, 0, stream>>>(counts, pbase, cursors, tile_expert, num_tiles);
  scatter_kernel<<<R_ / 256, 256, 0, stream>>>(topk_e, topk_w, pbase, cursors, prow_token, prow_w);

  for (int p = 0; p < NPH; p++) {
    int base = p * TPP;
    fc_gemm_kernel<<<dim3(H_ / BN, TPP), 256, 0, stream>>>(xbf, WtFc, bfc, prow_token,
                                                           tile_expert, num_tiles, zrow,
                                                           Hbuf, base);
    proj_gemm_kernel<<<dim3(D_ / BN, TPP), 256, 0, stream>>>(Hbuf, WtPj, bpj, prow_token,
                                                             prow_w, tile_expert, num_tiles,
                                                             out, base);
  }
}